// Round 7
// baseline (462.463 us; speedup 1.0000x reference)
//
#include <hip/hip_runtime.h>
#include <stdint.h>

typedef __attribute__((ext_vector_type(8))) short bf16x8;   // 8 bf16 in 4 VGPRs
typedef __attribute__((ext_vector_type(4))) short bf16x4;   // 4 bf16 in 2 VGPRs
typedef __attribute__((ext_vector_type(4))) float f32x4;
typedef __attribute__((ext_vector_type(4))) unsigned short u16x4;
typedef unsigned short u16;

__device__ __forceinline__ u16 f2b(float f) {               // round-half-up f32->bf16
  uint32_t u = __builtin_bit_cast(uint32_t, f);
  return (u16)((u + 0x8000u) >> 16);
}
__device__ __forceinline__ float b2f(u16 v) {
  uint32_t u = ((uint32_t)v) << 16;
  return __builtin_bit_cast(float, u);
}
__device__ __forceinline__ f32x4 mfma16(bf16x8 a, bf16x8 b, f32x4 c) {
  return __builtin_amdgcn_mfma_f32_16x16x32_bf16(a, b, c, 0, 0, 0);
}
__device__ __forceinline__ f32x4 mfma16x16(bf16x4 a, bf16x4 b, f32x4 c) {
#if __has_builtin(__builtin_amdgcn_mfma_f32_16x16x16bf16_1k)
  return __builtin_amdgcn_mfma_f32_16x16x16bf16_1k(a, b, c, 0, 0, 0);
#else
  f32x4 d;
  asm("v_mfma_f32_16x16x16_bf16 %0, %1, %2, %3" : "=v"(d) : "v"(a), "v"(b), "v"(c));
  return d;
#endif
}
__device__ __forceinline__ void gload_lds16(const void* g, void* l) {
  __builtin_amdgcn_global_load_lds((const __attribute__((address_space(1))) unsigned int*)g,
                                   (__attribute__((address_space(3))) unsigned int*)l, 16, 0, 0);
}

// ---------------- conversion / small kernels ----------------
__global__ __launch_bounds__(256) void cvt_k(const float* __restrict__ src, u16* __restrict__ dst, int n) {
  int i = (blockIdx.x * 256 + threadIdx.x) * 4;
  if (i >= n) return;
  float4 v = *(const float4*)(src + i);
  u16x4 o; o[0] = f2b(v.x); o[1] = f2b(v.y); o[2] = f2b(v.z); o[3] = f2b(v.w);
  *(u16x4*)(dst + i) = o;
}

__global__ __launch_bounds__(256) void bcat_k(const float* __restrict__ bq, const float* __restrict__ bk,
                                              const float* __restrict__ bv, float* __restrict__ bcat) {
  int i = blockIdx.x * 256 + threadIdx.x;   // 5120 total
  bcat[i] = (i < 2048) ? bq[i] : ((i < 4096) ? bk[i - 2048] : bv[i - 4096]);
}

__global__ void lam_k(const float* __restrict__ lq1, const float* __restrict__ lk1,
                      const float* __restrict__ lq2, const float* __restrict__ lk2,
                      float* __restrict__ lam) {
  int h = threadIdx.x;
  if (h < 16) {
    float d1 = 0.f, d2 = 0.f;
    for (int i = 0; i < 64; i++) {
      d1 += lq1[h * 64 + i] * lk1[h * 64 + i];
      d2 += lq2[h * 64 + i] * lk2[h * 64 + i];
    }
    lam[h] = 0.2f + __expf(d1) - __expf(d2);  // LAMBDA_INIT = 0.2
  }
}

// RoPE cos/sin table, layout [i][s]: tab[i*2048 + s] = {cos(s*10000^-i/32), sin(...)}
__global__ __launch_bounds__(256) void rope_tab_k(float2* __restrict__ tab) {
  int u = blockIdx.x * 256 + threadIdx.x;   // 65536
  int i = u >> 11, s = u & 2047;
  float inv = __expf(-9.210340371976184f * (float)i * (1.f / 32.f));
  float ang = (float)s * inv;
  tab[u] = make_float2(cosf(ang), sinf(ang));
}

// ---------------- GEMM QKV (128x128 tile, BK=32, 4 waves) + fused bias/RoPE/scale ----------------
#define KD 1024

__global__ __launch_bounds__(256) void gemm_qkv(
    const u16* __restrict__ A, const u16* __restrict__ B, const float* __restrict__ bcat,
    const float2* __restrict__ tab,
    u16* __restrict__ qout, u16* __restrict__ kout, u16* __restrict__ vout) {
  __shared__ __align__(16) u16 Al[128 * 32];
  __shared__ __align__(16) u16 Bl[128 * 32];
  const int t = threadIdx.x;
  const int w = t >> 6;
  const int l = t & 63;
  const int lr = l & 15, lg = l >> 4, lk8 = lg * 8;
  const int wm = (w >> 1) * 64, wn = (w & 1) * 64;
  const int n0 = blockIdx.x * 128, m0 = blockIdx.y * 128;
  f32x4 acc[4][4] = {};
  for (int k0 = 0; k0 < KD; k0 += 32) {
    __syncthreads();
#pragma unroll
    for (int i = 0; i < 2; i++) {
      int c = i * 256 + t;
      gload_lds16(A + (size_t)(m0 + (c >> 2)) * KD + k0 + (c & 3) * 8, (char*)Al + i * 4096 + w * 1024);
      gload_lds16(B + (size_t)(n0 + (c >> 2)) * KD + k0 + (c & 3) * 8, (char*)Bl + i * 4096 + w * 1024);
    }
    __syncthreads();
    bf16x8 af[4], bfr[4];
#pragma unroll
    for (int mi = 0; mi < 4; mi++) af[mi] = *(const bf16x8*)(Al + (wm + mi * 16 + lr) * 32 + lk8);
#pragma unroll
    for (int ni = 0; ni < 4; ni++) bfr[ni] = *(const bf16x8*)(Bl + (wn + ni * 16 + lr) * 32 + lk8);
#pragma unroll
    for (int mi = 0; mi < 4; mi++)
#pragma unroll
      for (int ni = 0; ni < 4; ni++)
        acc[mi][ni] = mfma16(af[mi], bfr[ni], acc[mi][ni]);
  }
  // ---- epilogue ----
  if (n0 >= 4096) {                 // V region: +bias, bf16, transposed out [b][h][d][S]
#pragma unroll
    for (int mi = 0; mi < 4; mi++) {
#pragma unroll
      for (int ni = 0; ni < 4; ni++) {
        int n = n0 + wn + ni * 16 + lr;
        int mbase = m0 + wm + mi * 16 + lg * 4;
        float bc = bcat[n];
        int nv = n - 4096, h = nv >> 6, d = nv & 63;
        int b = mbase >> 11, s = mbase & 2047;
        u16x4 pk;
#pragma unroll
        for (int r = 0; r < 4; r++) pk[r] = f2b(acc[mi][ni][r] + bc);
        *(u16x4*)(vout + ((size_t)(b * 16 + h) * 64 + d) * 2048 + s) = pk;
      }
    }
  } else {                          // Q/K region: +bias, RoPE, (Q also *0.125), scatter
    const bool isq = (n0 < 2048);
    u16* outp = isq ? qout : kout;
    const float scale = isq ? 0.125f : 1.f;
    const int nk0 = isq ? n0 : (n0 - 2048);
    const int hh = nk0 >> 7;
#pragma unroll
    for (int mi = 0; mi < 4; mi++) {
      int mbase = m0 + wm + mi * 16 + lg * 4;
#pragma unroll
      for (int nip = 0; nip < 2; nip++) {
        int i = nip * 16 + lr;                 // rotary pair index (<32)
        int nlo = n0 + wn + nip * 16 + lr;
        float blo = bcat[nlo], bhi = bcat[nlo + 32];
        int d = wn + nip * 16 + lr;
#pragma unroll
        for (int r = 0; r < 4; r++) {
          int m = mbase + r;
          int s = m & 2047, bb = m >> 11;
          float2 cs = tab[(i << 11) + s];
          float a = acc[mi][nip][r] + blo;
          float b2 = acc[mi][nip + 2][r] + bhi;
          float olo = (a * cs.x - b2 * cs.y) * scale;
          float ohi = (a * cs.y + b2 * cs.x) * scale;
          size_t rowb = ((size_t)(bb * 16 + hh) * 2048 + s) * 128;
          outp[rowb + d] = f2b(olo);
          outp[rowb + d + 32] = f2b(ohi);
        }
      }
    }
  }
}

__global__ __launch_bounds__(256) void gemm_wo(
    const u16* __restrict__ A, const u16* __restrict__ B, const float* __restrict__ bo,
    float* __restrict__ out) {
  __shared__ __align__(16) u16 Al[128 * 32];
  __shared__ __align__(16) u16 Bl[128 * 32];
  const int t = threadIdx.x;
  const int w = t >> 6;
  const int l = t & 63;
  const int lr = l & 15, lg = l >> 4, lk8 = lg * 8;
  const int wm = (w >> 1) * 64, wn = (w & 1) * 64;
  const int n0 = blockIdx.x * 128, m0 = blockIdx.y * 128;
  f32x4 acc[4][4] = {};
  for (int k0 = 0; k0 < KD; k0 += 32) {
    __syncthreads();
#pragma unroll
    for (int i = 0; i < 2; i++) {
      int c = i * 256 + t;
      gload_lds16(A + (size_t)(m0 + (c >> 2)) * KD + k0 + (c & 3) * 8, (char*)Al + i * 4096 + w * 1024);
      gload_lds16(B + (size_t)(n0 + (c >> 2)) * KD + k0 + (c & 3) * 8, (char*)Bl + i * 4096 + w * 1024);
    }
    __syncthreads();
    bf16x8 af[4], bfr[4];
#pragma unroll
    for (int mi = 0; mi < 4; mi++) af[mi] = *(const bf16x8*)(Al + (wm + mi * 16 + lr) * 32 + lk8);
#pragma unroll
    for (int ni = 0; ni < 4; ni++) bfr[ni] = *(const bf16x8*)(Bl + (wn + ni * 16 + lr) * 32 + lk8);
#pragma unroll
    for (int mi = 0; mi < 4; mi++)
#pragma unroll
      for (int ni = 0; ni < 4; ni++)
        acc[mi][ni] = mfma16(af[mi], bfr[ni], acc[mi][ni]);
  }
#pragma unroll
  for (int mi = 0; mi < 4; mi++) {
#pragma unroll
    for (int ni = 0; ni < 4; ni++) {
#pragma unroll
      for (int r = 0; r < 4; r++) {
        int m = m0 + wm + mi * 16 + lg * 4 + r;
        int n = n0 + wn + ni * 16 + lr;
        out[(size_t)m * 1024 + n] = acc[mi][ni][r] + bo[n];
      }
    }
  }
}

// ---------------- differential flash attention: register-only, no LDS, no barriers ----------------
// 2048 one-wave blocks; pairs (pr, 127-pr) of 16-row q-tiles => 129 iters each, KVB=16.
// Swapped QK^T: S^T = mfma_16x16x32(K-frag, Q-frag) -> lane holds S[k=lg*4+r][q=lr],
// which IS the B-frag of mfma_16x16x16 -> PV as O^T = V^T x P^T entirely in-register.
// Fixed-shift softmax (p = exp(s), scores bounded); l via per-lane partial sums + 2 shfl at end.
__global__ __launch_bounds__(64) void diff_attn(
    const u16* __restrict__ Q, const u16* __restrict__ Kk, const u16* __restrict__ V,
    const float* __restrict__ lamv, const float* __restrict__ hnw, u16* __restrict__ Aout) {
  const int l = threadIdx.x, lr = l & 15, lg = l >> 4;
  const int bid = (blockIdx.x & 7) * 256 + (blockIdx.x >> 3);   // XCD-aware bijective swizzle
  const int pr = bid & 63;
  const int h = (bid >> 6) & 15, b = bid >> 10;
  const size_t bh = (size_t)b * 16 + h;
  const u16* Qb = Q + bh * 2048 * 128;
  const u16* Kb = Kk + bh * 2048 * 128;
  const u16* Vb = V + bh * 64 * 2048;     // V^T: [64 d][2048 s]
  const float lam = lamv[h];

  for (int half = 0; half < 2; half++) {
    const int qt = half ? (127 - pr) : pr;
    const int q0 = qt * 16;
    bf16x8 qf[2][2];
#pragma unroll
    for (int hf = 0; hf < 2; hf++)
#pragma unroll
      for (int ds = 0; ds < 2; ds++)
        qf[hf][ds] = *(const bf16x8*)(Qb + (size_t)(q0 + lr) * 128 + hf * 64 + ds * 32 + lg * 8);
    f32x4 O1[4] = {}, O2[4] = {};
    float ls1 = 0.f, ls2 = 0.f;
    const int nkt = qt + 1;
    const u16* kp = Kb + (size_t)lr * 128 + lg * 8;
    const u16* vp = Vb + (size_t)lr * 2048 + lg * 4;
    for (int kt = 0; kt < nkt; kt++) {
      // K A-frags (row k0+lr): d-halves for matrix1 [0,64), matrix2 [64,128)
      bf16x8 kA10 = *(const bf16x8*)(kp);
      bf16x8 kA11 = *(const bf16x8*)(kp + 32);
      bf16x8 kA20 = *(const bf16x8*)(kp + 64);
      bf16x8 kA21 = *(const bf16x8*)(kp + 96);
      // V^T A-frags: V^T[dt*16+lr][k0+lg*4 .. +3]
      bf16x4 vf[4];
#pragma unroll
      for (int dt = 0; dt < 4; dt++)
        vf[dt] = *(const bf16x4*)(vp + (size_t)dt * 32768);
      // swapped QK^T: lane -> S[k=k0+lg*4+r][q=q0+lr]
      f32x4 s1 = {}, s2 = {};
      s1 = mfma16(kA10, qf[0][0], s1);
      s1 = mfma16(kA11, qf[0][1], s1);
      s2 = mfma16(kA20, qf[1][0], s2);
      s2 = mfma16(kA21, qf[1][1], s2);
      if (kt == nkt - 1) {          // diagonal tile: mask k>q  <=>  lg*4+r > lr
#pragma unroll
        for (int r = 0; r < 4; r++)
          if (lg * 4 + r > lr) { s1[r] = -1e30f; s2[r] = -1e30f; }
      }
      float p1[4], p2[4];
#pragma unroll
      for (int r = 0; r < 4; r++) { p1[r] = __expf(s1[r]); p2[r] = __expf(s2[r]); }
      ls1 += p1[0] + p1[1] + p1[2] + p1[3];
      ls2 += p2[0] + p2[1] + p2[2] + p2[3];
      // pack P^T fragments (bf16x4, k = lg*4+{0..3}) fully in-register
      uint32_t a0 = __builtin_bit_cast(uint32_t, p1[0]) + 0x8000u;
      uint32_t a1 = __builtin_bit_cast(uint32_t, p1[1]) + 0x8000u;
      uint32_t a2 = __builtin_bit_cast(uint32_t, p1[2]) + 0x8000u;
      uint32_t a3 = __builtin_bit_cast(uint32_t, p1[3]) + 0x8000u;
      uint2 u1 = {__builtin_amdgcn_perm(a1, a0, 0x07060302u),
                  __builtin_amdgcn_perm(a3, a2, 0x07060302u)};
      uint32_t c0 = __builtin_bit_cast(uint32_t, p2[0]) + 0x8000u;
      uint32_t c1 = __builtin_bit_cast(uint32_t, p2[1]) + 0x8000u;
      uint32_t c2 = __builtin_bit_cast(uint32_t, p2[2]) + 0x8000u;
      uint32_t c3 = __builtin_bit_cast(uint32_t, p2[3]) + 0x8000u;
      uint2 u2 = {__builtin_amdgcn_perm(c1, c0, 0x07060302u),
                  __builtin_amdgcn_perm(c3, c2, 0x07060302u)};
      bf16x4 pT1 = __builtin_bit_cast(bf16x4, u1);
      bf16x4 pT2 = __builtin_bit_cast(bf16x4, u2);
      // PV: O^T[d][q] += V^T x P^T  (16x16x16)
#pragma unroll
      for (int dt = 0; dt < 4; dt++) {
        O1[dt] = mfma16x16(vf[dt], pT1, O1[dt]);
        O2[dt] = mfma16x16(vf[dt], pT2, O2[dt]);
      }
      kp += 16 * 128;
      vp += 16;
    }
    // reduce l across the 4 lg lanes of each q-column
    ls1 += __shfl_xor(ls1, 16); ls1 += __shfl_xor(ls1, 32);
    ls2 += __shfl_xor(ls2, 16); ls2 += __shfl_xor(ls2, 32);
    float i1 = 1.f / ls1, i2 = lam / ls2;
    // diff-combine + RMS over d (lane holds d = dt*16+lg*4+r for q=lr)
    float ss = 0.f;
    f32x4 ov[4];
#pragma unroll
    for (int dt = 0; dt < 4; dt++)
#pragma unroll
      for (int r = 0; r < 4; r++) {
        float o = O1[dt][r] * i1 - O2[dt][r] * i2;
        ov[dt][r] = o;
        ss += o * o;
      }
    ss += __shfl_xor(ss, 16); ss += __shfl_xor(ss, 32);
    float rr = rsqrtf(ss * (1.f / 64.f) + 1e-6f) * 0.8f;
#pragma unroll
    for (int dt = 0; dt < 4; dt++) {
      float4 hw4 = *(const float4*)(hnw + h * 64 + dt * 16 + lg * 4);
      u16x4 pk;
      pk[0] = f2b(ov[dt][0] * rr * hw4.x);
      pk[1] = f2b(ov[dt][1] * rr * hw4.y);
      pk[2] = f2b(ov[dt][2] * rr * hw4.z);
      pk[3] = f2b(ov[dt][3] * rr * hw4.w);
      *(u16x4*)(Aout + ((size_t)(b * 2048 + q0 + lr)) * 1024 + h * 64 + dt * 16 + lg * 4) = pk;
    }
  }
}

// ---------------- launch ----------------
extern "C" void kernel_launch(void* const* d_in, const int* in_sizes, int n_in,
                              void* d_out, int out_size, void* d_ws, size_t ws_size,
                              hipStream_t stream) {
  const float* x   = (const float*)d_in[0];
  const float* Wq  = (const float*)d_in[1];
  const float* bq  = (const float*)d_in[2];
  const float* Wk  = (const float*)d_in[3];
  const float* bk  = (const float*)d_in[4];
  const float* Wv  = (const float*)d_in[5];
  const float* bv  = (const float*)d_in[6];
  const float* Wo  = (const float*)d_in[7];
  const float* bo  = (const float*)d_in[8];
  const float* hnw = (const float*)d_in[9];
  const float* lq1 = (const float*)d_in[10];
  const float* lk1 = (const float*)d_in[11];
  const float* lq2 = (const float*)d_in[12];
  const float* lk2 = (const float*)d_in[13];
  float* out = (float*)d_out;
  char* ws = (char*)d_ws;

  u16*   x_bf  = (u16*)(ws);                 //  8,388,608 B
  u16*   wcat  = (u16*)(ws + 8388608);       // 10,485,760 B  (Wq|Wk|Wv bf16)
  u16*   wo_bf = (u16*)(ws + 18874368);      //  2,097,152 B
  float* bcat  = (float*)(ws + 20971520);    //     20,480 B
  float* lam   = (float*)(ws + 20992000);    //         64 B
  u16*   q_r   = (u16*)(ws + 20992064);      // 16,777,216 B  (B,H,S,128)
  u16*   k_r   = (u16*)(ws + 37769280);      // 16,777,216 B
  u16*   v_t   = (u16*)(ws + 54546496);      //  8,388,608 B  (B,H,64,S)  V transposed
  u16*   a_out = (u16*)(ws + 62935104);      //  8,388,608 B
  float2* tab  = (float2*)(ws + 71323712);   //    524,288 B  RoPE table [32][2048]

  cvt_k<<<4096, 256, 0, stream>>>(x, x_bf, 4194304);
  cvt_k<<<2048, 256, 0, stream>>>(Wq, wcat, 2097152);
  cvt_k<<<2048, 256, 0, stream>>>(Wk, wcat + 2097152, 2097152);
  cvt_k<<<1024, 256, 0, stream>>>(Wv, wcat + 4194304, 1048576);
  cvt_k<<<1024, 256, 0, stream>>>(Wo, wo_bf, 1048576);
  bcat_k<<<20, 256, 0, stream>>>(bq, bk, bv, bcat);
  lam_k<<<1, 64, 0, stream>>>(lq1, lk1, lq2, lk2, lam);
  rope_tab_k<<<256, 256, 0, stream>>>(tab);
  gemm_qkv<<<dim3(40, 32), 256, 0, stream>>>(x_bf, wcat, bcat, tab, q_r, k_r, v_t);
  diff_attn<<<2048, 64, 0, stream>>>(q_r, k_r, v_t, lam, hnw, a_out);
  gemm_wo<<<dim3(8, 32), 256, 0, stream>>>(a_out, wo_bf, bo, out);
}